// Round 1
// baseline (1705.219 us; speedup 1.0000x reference)
//
#include <hip/hip_runtime.h>

#define BB 4
#define SS 4096
#define HH 128
#define SCALE 0.08838834764831845f   // 1/sqrt(128)
#define NEG_INF (-1e30f)

// ---------------- QKV projection: qkv = X @ W^T + b ----------------
// X: [B*S, H] fp32, W: [3H, H] fp32, b: [3H]
// Writes Q, K, V each [B*S, H] fp32 into workspace.
__global__ __launch_bounds__(128) void qkv_proj(
    const float* __restrict__ X, const float* __restrict__ W,
    const float* __restrict__ bias, float* __restrict__ Q,
    float* __restrict__ K, float* __restrict__ V)
{
    const int row = blockIdx.x;      // 0 .. B*S-1
    const int t   = threadIdx.x;     // 0 .. 127
    __shared__ __align__(16) float xr[HH];
    xr[t] = X[(size_t)row * HH + t];
    __syncthreads();

    const float* wq = W + (size_t)t * HH;
    const float* wk = W + (size_t)(t + HH) * HH;
    const float* wv = W + (size_t)(t + 2 * HH) * HH;
    float aq = 0.f, ak = 0.f, av = 0.f;
#pragma unroll
    for (int k = 0; k < HH; k += 4) {
        const float4 x4 = *reinterpret_cast<const float4*>(xr + k);
        const float4 q4 = *reinterpret_cast<const float4*>(wq + k);
        const float4 k4 = *reinterpret_cast<const float4*>(wk + k);
        const float4 v4 = *reinterpret_cast<const float4*>(wv + k);
        aq += x4.x * q4.x + x4.y * q4.y + x4.z * q4.z + x4.w * q4.w;
        ak += x4.x * k4.x + x4.y * k4.y + x4.z * k4.z + x4.w * k4.w;
        av += x4.x * v4.x + x4.y * v4.y + x4.z * v4.z + x4.w * v4.w;
    }
    const size_t o = (size_t)row * HH + t;
    Q[o] = aq + bias[t];
    K[o] = ak + bias[t + HH];
    V[o] = av + bias[t + 2 * HH];
}

// ---------------- Flash attention (fp32 baseline) ----------------
// grid: (S/BM, B), block: 128 threads.
// Per thread: 4 query rows x 2 score cols; PV: 4 rows x 8 out cols.
#define BM 32
#define BN 32
#define LQ (HH + 4)   // 132 floats: padded stride, <=2-way bank aliasing
#define LP (BN + 4)   // 36

__global__ __launch_bounds__(128) void attn_fp32(
    const float* __restrict__ Q, const float* __restrict__ K,
    const float* __restrict__ V, float* __restrict__ out)
{
    __shared__ __align__(16) float sQ[BM][LQ];
    __shared__ __align__(16) float sK[BN][LQ];
    __shared__ __align__(16) float sV[BN][LQ];
    __shared__ __align__(16) float sP[BM][LP];

    const int b   = blockIdx.y;
    const int qt  = blockIdx.x;
    const int tid = (int)threadIdx.x;   // 0..127
    const int cb  = tid & 15;           // 0..15
    const int rb  = tid >> 4;           // 0..7
    const int r0  = rb * 4;             // first of this thread's 4 rows

    const float* Qb = Q + ((size_t)b * SS + (size_t)qt * BM) * HH;
    const float* Kb = K + (size_t)b * SS * HH;
    const float* Vb = V + (size_t)b * SS * HH;

    // load Q tile (BM x H): 1024 float4, 8 per thread, coalesced
    for (int i = tid; i < BM * (HH / 4); i += 128) {
        const int r = i >> 5;
        const int c = (i & 31) << 2;
        *reinterpret_cast<float4*>(&sQ[r][c]) =
            *reinterpret_cast<const float4*>(Qb + (size_t)r * HH + c);
    }

    float m[4], l[4], o[4][8];
#pragma unroll
    for (int r = 0; r < 4; ++r) {
        m[r] = NEG_INF; l[r] = 0.f;
#pragma unroll
        for (int c = 0; c < 8; ++c) o[r][c] = 0.f;
    }

    for (int kt = 0; kt < SS; kt += BN) {
        __syncthreads();   // prior iter's reads of sK/sV/sP done (also covers Q load on iter 0)
        for (int i = tid; i < BN * (HH / 4); i += 128) {
            const int r = i >> 5;
            const int c = (i & 31) << 2;
            *reinterpret_cast<float4*>(&sK[r][c]) =
                *reinterpret_cast<const float4*>(Kb + (size_t)(kt + r) * HH + c);
            *reinterpret_cast<float4*>(&sV[r][c]) =
                *reinterpret_cast<const float4*>(Vb + (size_t)(kt + r) * HH + c);
        }
        __syncthreads();

        // ---- scores: rows r0..r0+3, cols {cb, cb+16} ----
        float s[4][2] = {{0.f,0.f},{0.f,0.f},{0.f,0.f},{0.f,0.f}};
#pragma unroll
        for (int k = 0; k < HH; k += 4) {
            const float4 k0 = *reinterpret_cast<const float4*>(&sK[cb][k]);
            const float4 k1 = *reinterpret_cast<const float4*>(&sK[cb + 16][k]);
#pragma unroll
            for (int r = 0; r < 4; ++r) {
                const float4 q4 = *reinterpret_cast<const float4*>(&sQ[r0 + r][k]);
                s[r][0] += q4.x*k0.x + q4.y*k0.y + q4.z*k0.z + q4.w*k0.w;
                s[r][1] += q4.x*k1.x + q4.y*k1.y + q4.z*k1.z + q4.w*k1.w;
            }
        }

        // ---- online softmax update (reduce across the 16 cb-lanes) ----
#pragma unroll
        for (int r = 0; r < 4; ++r) {
            const float s0 = s[r][0] * SCALE;
            const float s1 = s[r][1] * SCALE;
            float rm = fmaxf(s0, s1);
            rm = fmaxf(rm, __shfl_xor(rm, 1));
            rm = fmaxf(rm, __shfl_xor(rm, 2));
            rm = fmaxf(rm, __shfl_xor(rm, 4));
            rm = fmaxf(rm, __shfl_xor(rm, 8));
            const float mn = fmaxf(m[r], rm);
            const float p0 = __expf(s0 - mn);
            const float p1 = __expf(s1 - mn);
            float ls = p0 + p1;
            ls += __shfl_xor(ls, 1);
            ls += __shfl_xor(ls, 2);
            ls += __shfl_xor(ls, 4);
            ls += __shfl_xor(ls, 8);
            const float alpha = __expf(m[r] - mn);
            m[r] = mn;
            l[r] = l[r] * alpha + ls;
            sP[r0 + r][cb]      = p0;
            sP[r0 + r][cb + 16] = p1;
#pragma unroll
            for (int c = 0; c < 8; ++c) o[r][c] *= alpha;
        }
        __syncthreads();

        // ---- PV accumulate: cols cb*4+{0..3} and 64+cb*4+{0..3} ----
#pragma unroll
        for (int n4 = 0; n4 < BN; n4 += 4) {
            float4 p[4];
#pragma unroll
            for (int r = 0; r < 4; ++r)
                p[r] = *reinterpret_cast<const float4*>(&sP[r0 + r][n4]);
#pragma unroll
            for (int j = 0; j < 4; ++j) {
                const float4 v0 = *reinterpret_cast<const float4*>(&sV[n4 + j][cb * 4]);
                const float4 v1 = *reinterpret_cast<const float4*>(&sV[n4 + j][64 + cb * 4]);
#pragma unroll
                for (int r = 0; r < 4; ++r) {
                    const float pr = reinterpret_cast<const float*>(&p[r])[j];
                    o[r][0] += pr * v0.x; o[r][1] += pr * v0.y;
                    o[r][2] += pr * v0.z; o[r][3] += pr * v0.w;
                    o[r][4] += pr * v1.x; o[r][5] += pr * v1.y;
                    o[r][6] += pr * v1.z; o[r][7] += pr * v1.w;
                }
            }
        }
    }

    // ---- epilogue: normalize and store ----
    float* ob = out + ((size_t)b * SS + (size_t)qt * BM) * HH;
#pragma unroll
    for (int r = 0; r < 4; ++r) {
        const float inv = 1.f / l[r];
        float4 w0, w1;
        w0.x = o[r][0]*inv; w0.y = o[r][1]*inv; w0.z = o[r][2]*inv; w0.w = o[r][3]*inv;
        w1.x = o[r][4]*inv; w1.y = o[r][5]*inv; w1.z = o[r][6]*inv; w1.w = o[r][7]*inv;
        *reinterpret_cast<float4*>(ob + (size_t)(r0 + r) * HH + cb * 4)      = w0;
        *reinterpret_cast<float4*>(ob + (size_t)(r0 + r) * HH + 64 + cb * 4) = w1;
    }
}

extern "C" void kernel_launch(void* const* d_in, const int* in_sizes, int n_in,
                              void* d_out, int out_size, void* d_ws, size_t ws_size,
                              hipStream_t stream) {
    const float* X = (const float*)d_in[0];   // [4,4096,128]
    const float* W = (const float*)d_in[1];   // [384,128]
    const float* bias = (const float*)d_in[2];// [384]
    float* out = (float*)d_out;               // [4,4096,128]

    float* Qw = (float*)d_ws;
    float* Kw = Qw + (size_t)BB * SS * HH;
    float* Vw = Kw + (size_t)BB * SS * HH;

    qkv_proj<<<BB * SS, 128, 0, stream>>>(X, W, bias, Qw, Kw, Vw);
    attn_fp32<<<dim3(SS / BM, BB), 128, 0, stream>>>(Qw, Kw, Vw, out);
}

// Round 3
// 265.266 us; speedup vs baseline: 6.4283x; 6.4283x over previous
//
#include <hip/hip_runtime.h>
#include <hip/hip_fp16.h>

typedef _Float16 f16;
typedef __attribute__((ext_vector_type(8))) _Float16 f16x8;
typedef __attribute__((ext_vector_type(4))) float f32x4;
typedef __attribute__((ext_vector_type(4))) unsigned int u32x4;
typedef __attribute__((ext_vector_type(2))) unsigned int u32x2;

#define BB 4
#define SS 4096
#define HH 128
// log2(e)/sqrt(128)
#define SC2 0.12752462157076558f

union H2U { __half2 h; unsigned int u; };
union VU { u32x4 v; unsigned short s[8]; };

// ================= QKV projection: f16 MFMA GEMM =================
// X [16384,128] fp32, W [384,128] fp32, bias [384] fp32 -> Qh/Kh/Vh f16
#define LXS 136
__global__ __launch_bounds__(256) void qkv_gemm(
    const float* __restrict__ X, const float* __restrict__ W,
    const float* __restrict__ bias, f16* __restrict__ Qh,
    f16* __restrict__ Kh, f16* __restrict__ Vh)
{
    __shared__ f16 sX[128 * LXS];
    __shared__ f16 sW[64 * LXS];
    const int bx = blockIdx.x, by = blockIdx.y;
    const int t = threadIdx.x;

    {   // stage X tile [128][128] fp32 -> f16
        const int r = t >> 1, h = t & 1;
        const float* src = X + (size_t)(bx * 128 + r) * HH + h * 64;
        f16* dst = sX + r * LXS + h * 64;
#pragma unroll
        for (int i = 0; i < 16; ++i) {
            float4 v = ((const float4*)src)[i];
            __half2 a = __floats2half2_rn(v.x, v.y);
            __half2 b = __floats2half2_rn(v.z, v.w);
            ((__half2*)dst)[2 * i] = a;
            ((__half2*)dst)[2 * i + 1] = b;
        }
    }
    {   // stage W tile [64][128]
        const int r = t >> 2, q = t & 3;
        const float* src = W + (size_t)(by * 64 + r) * HH + q * 32;
        f16* dst = sW + r * LXS + q * 32;
#pragma unroll
        for (int i = 0; i < 8; ++i) {
            float4 v = ((const float4*)src)[i];
            __half2 a = __floats2half2_rn(v.x, v.y);
            __half2 b = __floats2half2_rn(v.z, v.w);
            ((__half2*)dst)[2 * i] = a;
            ((__half2*)dst)[2 * i + 1] = b;
        }
    }
    __syncthreads();

    const int w = t >> 6, lane = t & 63;
    const int c = lane & 15, quad = lane >> 4;

    f32x4 acc[2][4];
#pragma unroll
    for (int mt = 0; mt < 2; ++mt)
#pragma unroll
        for (int nt = 0; nt < 4; ++nt) acc[mt][nt] = (f32x4)0.f;

#pragma unroll
    for (int kc = 0; kc < 4; ++kc) {
        f16x8 af[2], bf[4];
#pragma unroll
        for (int mt = 0; mt < 2; ++mt)
            af[mt] = *(const f16x8*)&sX[(w * 32 + mt * 16 + c) * LXS + kc * 32 + quad * 8];
#pragma unroll
        for (int nt = 0; nt < 4; ++nt)
            bf[nt] = *(const f16x8*)&sW[(nt * 16 + c) * LXS + kc * 32 + quad * 8];
#pragma unroll
        for (int mt = 0; mt < 2; ++mt)
#pragma unroll
            for (int nt = 0; nt < 4; ++nt)
                acc[mt][nt] = __builtin_amdgcn_mfma_f32_16x16x32_f16(af[mt], bf[nt], acc[mt][nt], 0, 0, 0);
    }

    // epilogue: bias add, f16 convert, scatter into Q/K/V
    f16* outp = (by < 2) ? Qh : (by < 4) ? Kh : Vh;
    const int cbase = (by & 1) * 64;
#pragma unroll
    for (int nt = 0; nt < 4; ++nt) {
        const int cc = cbase + nt * 16 + c;
        const float bv = bias[by * 64 + nt * 16 + c];
#pragma unroll
        for (int mt = 0; mt < 2; ++mt) {
#pragma unroll
            for (int r = 0; r < 4; ++r) {
                const int row = bx * 128 + w * 32 + mt * 16 + quad * 4 + r;
                outp[(size_t)row * HH + cc] = (f16)(acc[mt][nt][r] + bv);
            }
        }
    }
}

// ================= Flash attention, f16 MFMA =================
// grid 256 (batch = bid&3 for XCD/L2 locality), block 128 = 2 waves x 32 queries
#define BM 64
#define BN 64
#define NSTEP (SS / BN)
#define LK 136   // sK row stride (f16): 64 rows x 128 + pad8
#define LV 88    // sVt row stride: 128 head-rows x (64 keys + pad 24)
#define LP 88    // sP row stride: 32 query-rows x (64 keys + pad 24)

__global__ __launch_bounds__(128, 1) void attn_mfma(
    const f16* __restrict__ Qh, const f16* __restrict__ Kh,
    const f16* __restrict__ Vh, float* __restrict__ out)
{
    __shared__ f16 sK[BN * LK];        // 17408 B
    __shared__ f16 sVt[HH * LV];       // 22528 B
    __shared__ f16 sP[2][32 * LP];     // 11264 B
    __shared__ float sA[2][32];

    const int bid = blockIdx.x;
    const int batch = bid & 3;
    const int qtile = bid >> 2;
    const int t = threadIdx.x;
    const int w = t >> 6, lane = t & 63;
    const int c = lane & 15, quad = lane >> 4;

    const f16* Qb = Qh + (size_t)batch * SS * HH;
    const f16* Kb = Kh + (size_t)batch * SS * HH;
    const f16* Vb = Vh + (size_t)batch * SS * HH;
    const int qbase = qtile * BM + w * 32;

    // Q fragments (B-operand): B[k][n=query], n = lane&15, k = quad*8+j (+32*kc)
    f16x8 qf[2][4];
#pragma unroll
    for (int qt = 0; qt < 2; ++qt)
#pragma unroll
        for (int kc = 0; kc < 4; ++kc)
            qf[qt][kc] = *(const f16x8*)(Qb + (size_t)(qbase + qt * 16 + c) * HH + kc * 32 + quad * 8);

    // staging assignments
    const int kr = t >> 1, kh = t & 1;          // K: 2 threads/row
    const f16* kgp = Kb + (size_t)kr * HH + kh * 64;
    f16* ksp = sK + kr * LK + kh * 64;
    const int vkp = t & 31, vhq = t >> 5;       // V: key pair 2*vkp, head group
    const f16* vgp = Vb + (size_t)(2 * vkp) * HH;

    u32x4 kbuf[8], vb0[4], vb1[4];
#pragma unroll
    for (int i = 0; i < 8; ++i) kbuf[i] = *(const u32x4*)(kgp + i * 8);
#pragma unroll
    for (int p = 0; p < 4; ++p) {
        const int hg = vhq * 4 + p;
        vb0[p] = *(const u32x4*)(vgp + hg * 8);
        vb1[p] = *(const u32x4*)(vgp + HH + hg * 8);
    }

    f32x4 oacc[2][8];
#pragma unroll
    for (int mt = 0; mt < 2; ++mt)
#pragma unroll
        for (int nt = 0; nt < 8; ++nt) oacc[mt][nt] = (f32x4)0.f;
    float m_[2] = {-1e30f, -1e30f}, l_[2] = {0.f, 0.f};

    for (int step = 0; step < NSTEP; ++step) {
        __syncthreads();
        // write staged K tile
#pragma unroll
        for (int i = 0; i < 8; ++i) *(u32x4*)(ksp + i * 8) = kbuf[i];
        // write staged V transposed (pair-packed b32)
#pragma unroll
        for (int p = 0; p < 4; ++p) {
            const int hg = vhq * 4 + p;
            VU a, b; a.v = vb0[p]; b.v = vb1[p];
#pragma unroll
            for (int i = 0; i < 8; ++i) {
                unsigned int pk = (unsigned int)a.s[i] | ((unsigned int)b.s[i] << 16);
                *(unsigned int*)&sVt[(hg * 8 + i) * LV + 2 * vkp] = pk;
            }
        }
        __syncthreads();
        // prefetch next tile (in flight during compute)
        if (step + 1 < NSTEP) {
            const f16* kg = kgp + (size_t)(step + 1) * BN * HH;
#pragma unroll
            for (int i = 0; i < 8; ++i) kbuf[i] = *(const u32x4*)(kg + i * 8);
            const f16* vg = vgp + (size_t)(step + 1) * BN * HH;
#pragma unroll
            for (int p = 0; p < 4; ++p) {
                const int hg = vhq * 4 + p;
                vb0[p] = *(const u32x4*)(vg + hg * 8);
                vb1[p] = *(const u32x4*)(vg + HH + hg * 8);
            }
        }

        // ---- S^T = K . Q^T : rows = keys, cols = queries ----
        f32x4 sacc[4][2];
#pragma unroll
        for (int km = 0; km < 4; ++km)
#pragma unroll
            for (int qt = 0; qt < 2; ++qt) sacc[km][qt] = (f32x4)0.f;
#pragma unroll
        for (int kc = 0; kc < 4; ++kc) {
#pragma unroll
            for (int km = 0; km < 4; ++km) {
                f16x8 kf = *(const f16x8*)&sK[(km * 16 + c) * LK + kc * 32 + quad * 8];
#pragma unroll
                for (int qt = 0; qt < 2; ++qt)
                    sacc[km][qt] = __builtin_amdgcn_mfma_f32_16x16x32_f16(kf, qf[qt][kc], sacc[km][qt], 0, 0, 0);
            }
        }

        // ---- online softmax (per query col = lane&15, per qt) ----
#pragma unroll
        for (int qt = 0; qt < 2; ++qt) {
            float mx = sacc[0][qt][0];
#pragma unroll
            for (int km = 0; km < 4; ++km)
#pragma unroll
                for (int r = 0; r < 4; ++r) mx = fmaxf(mx, sacc[km][qt][r]);
            mx = fmaxf(mx, __shfl_xor(mx, 16));
            mx = fmaxf(mx, __shfl_xor(mx, 32));
            const float mn = fmaxf(m_[qt], mx);
            const float alpha = exp2f((m_[qt] - mn) * SC2);
            m_[qt] = mn;
            const float tb = mn * SC2;
            float ls = 0.f;
#pragma unroll
            for (int km = 0; km < 4; ++km) {
                float p0 = exp2f(sacc[km][qt][0] * SC2 - tb);
                float p1 = exp2f(sacc[km][qt][1] * SC2 - tb);
                float p2 = exp2f(sacc[km][qt][2] * SC2 - tb);
                float p3 = exp2f(sacc[km][qt][3] * SC2 - tb);
                ls += (p0 + p1) + (p2 + p3);
                H2U u0, u1;
                u0.h = __floats2half2_rn(p0, p1);
                u1.h = __floats2half2_rn(p2, p3);
                u32x2 pk; pk.x = u0.u; pk.y = u1.u;
                *(u32x2*)&sP[w][(qt * 16 + c) * LP + km * 16 + quad * 4] = pk;
            }
            ls += __shfl_xor(ls, 16);
            ls += __shfl_xor(ls, 32);
            l_[qt] = l_[qt] * alpha + ls;
            if (quad == 0) sA[w][qt * 16 + c] = alpha;
        }

        // ---- rescale O by alpha (per output row = query) ----
#pragma unroll
        for (int mt = 0; mt < 2; ++mt) {
            f32x4 av = *(const f32x4*)&sA[w][mt * 16 + quad * 4];
#pragma unroll
            for (int nt = 0; nt < 8; ++nt)
#pragma unroll
                for (int r = 0; r < 4; ++r) oacc[mt][nt][r] *= av[r];
        }

        // ---- O += P . V ----
#pragma unroll
        for (int kc2 = 0; kc2 < 2; ++kc2) {
            f16x8 pf[2];
#pragma unroll
            for (int mt = 0; mt < 2; ++mt)
                pf[mt] = *(const f16x8*)&sP[w][(mt * 16 + c) * LP + kc2 * 32 + quad * 8];
#pragma unroll
            for (int nt = 0; nt < 8; ++nt) {
                f16x8 vf = *(const f16x8*)&sVt[(nt * 16 + c) * LV + kc2 * 32 + quad * 8];
#pragma unroll
                for (int mt = 0; mt < 2; ++mt)
                    oacc[mt][nt] = __builtin_amdgcn_mfma_f32_16x16x32_f16(pf[mt], vf, oacc[mt][nt], 0, 0, 0);
            }
        }
    }

    // ---- epilogue: normalize by l, store fp32 ----
#pragma unroll
    for (int qt = 0; qt < 2; ++qt)
        if (quad == 0) sA[w][qt * 16 + c] = 1.f / l_[qt];
    float* ob = out + (size_t)(batch * SS + qbase) * HH;
#pragma unroll
    for (int mt = 0; mt < 2; ++mt) {
        f32x4 lv = *(const f32x4*)&sA[w][mt * 16 + quad * 4];
#pragma unroll
        for (int r = 0; r < 4; ++r) {
            const int row = mt * 16 + quad * 4 + r;
#pragma unroll
            for (int nt = 0; nt < 8; ++nt)
                ob[(size_t)row * HH + nt * 16 + c] = oacc[mt][nt][r] * lv[r];
        }
    }
}

extern "C" void kernel_launch(void* const* d_in, const int* in_sizes, int n_in,
                              void* d_out, int out_size, void* d_ws, size_t ws_size,
                              hipStream_t stream) {
    const float* X = (const float*)d_in[0];
    const float* W = (const float*)d_in[1];
    const float* bias = (const float*)d_in[2];
    float* out = (float*)d_out;

    f16* Qh = (f16*)d_ws;
    f16* Kh = Qh + (size_t)BB * SS * HH;
    f16* Vh = Kh + (size_t)BB * SS * HH;

    qkv_gemm<<<dim3(128, 6), 256, 0, stream>>>(X, W, bias, Qh, Kh, Vh);
    attn_mfma<<<256, 128, 0, stream>>>(Qh, Kh, Vh, out);
}

// Round 4
// 157.526 us; speedup vs baseline: 10.8250x; 1.6840x over previous
//
#include <hip/hip_runtime.h>
#include <hip/hip_fp16.h>

typedef _Float16 f16;
typedef __attribute__((ext_vector_type(8))) _Float16 f16x8;
typedef __attribute__((ext_vector_type(4))) float f32x4;
typedef __attribute__((ext_vector_type(4))) unsigned int u32x4;
typedef __attribute__((ext_vector_type(2))) unsigned int u32x2;

#define BB 4
#define SS 4096
#define HH 128
// log2(e)/sqrt(128)
#define SC2 0.12752462157076558f

union H2U { __half2 h; unsigned int u; };
union VU { u32x4 v; unsigned short s[8]; };
union F8U { u32x4 u; f16x8 h; };

// ================= QKV projection: f16 MFMA GEMM =================
// X [16384,128] fp32 -> A-fragments direct from global; W tile in LDS.
// Block: 256 thr = 4 waves, covers 128 rows x 64 cols. Grid (128, 6).
#define LW 136
__global__ __launch_bounds__(256) void qkv_gemm(
    const float* __restrict__ X, const float* __restrict__ W,
    const float* __restrict__ bias, f16* __restrict__ Qh,
    f16* __restrict__ Kh, f16* __restrict__ Vh)
{
    __shared__ f16 sW[64 * LW];
    const int bx = blockIdx.x, by = blockIdx.y;
    const int t = threadIdx.x;
    const int w = t >> 6, lane = t & 63;
    const int c = lane & 15, quad = lane >> 4;

    // A fragments straight from global (fp32 -> f16 in-register)
    f16x8 af[2][4];
    const int rbase = bx * 128 + w * 32;
#pragma unroll
    for (int mt = 0; mt < 2; ++mt) {
        const float* xr = X + (size_t)(rbase + mt * 16 + c) * HH + quad * 8;
#pragma unroll
        for (int kc = 0; kc < 4; ++kc) {
            float4 a = *(const float4*)(xr + kc * 32);
            float4 b = *(const float4*)(xr + kc * 32 + 4);
            H2U u0, u1, u2, u3;
            u0.h = __floats2half2_rn(a.x, a.y);
            u1.h = __floats2half2_rn(a.z, a.w);
            u2.h = __floats2half2_rn(b.x, b.y);
            u3.h = __floats2half2_rn(b.z, b.w);
            F8U pk; pk.u.x = u0.u; pk.u.y = u1.u; pk.u.z = u2.u; pk.u.w = u3.u;
            af[mt][kc] = pk.h;
        }
    }

    {   // stage W tile [64][128] fp32 -> f16 LDS
        const int r = t >> 2, q = t & 3;
        const float* src = W + (size_t)(by * 64 + r) * HH + q * 32;
        f16* dst = sW + r * LW + q * 32;
#pragma unroll
        for (int i = 0; i < 8; ++i) {
            float4 v = ((const float4*)src)[i];
            __half2 a = __floats2half2_rn(v.x, v.y);
            __half2 b = __floats2half2_rn(v.z, v.w);
            ((__half2*)dst)[2 * i] = a;
            ((__half2*)dst)[2 * i + 1] = b;
        }
    }
    __syncthreads();

    f32x4 acc[2][4];
#pragma unroll
    for (int mt = 0; mt < 2; ++mt)
#pragma unroll
        for (int nt = 0; nt < 4; ++nt) acc[mt][nt] = (f32x4)0.f;

#pragma unroll
    for (int kc = 0; kc < 4; ++kc) {
        f16x8 bf[4];
#pragma unroll
        for (int nt = 0; nt < 4; ++nt)
            bf[nt] = *(const f16x8*)&sW[(nt * 16 + c) * LW + kc * 32 + quad * 8];
#pragma unroll
        for (int mt = 0; mt < 2; ++mt)
#pragma unroll
            for (int nt = 0; nt < 4; ++nt)
                acc[mt][nt] = __builtin_amdgcn_mfma_f32_16x16x32_f16(af[mt][kc], bf[nt], acc[mt][nt], 0, 0, 0);
    }

    // epilogue: bias add, f16 convert, scatter into Q/K/V
    f16* outp = (by < 2) ? Qh : (by < 4) ? Kh : Vh;
    const int cbase = (by & 1) * 64;
#pragma unroll
    for (int nt = 0; nt < 4; ++nt) {
        const int cc = cbase + nt * 16 + c;
        const float bv = bias[by * 64 + nt * 16 + c];
#pragma unroll
        for (int mt = 0; mt < 2; ++mt) {
#pragma unroll
            for (int r = 0; r < 4; ++r) {
                const int row = rbase + mt * 16 + quad * 4 + r;
                outp[(size_t)row * HH + cc] = (f16)(acc[mt][nt][r] + bv);
            }
        }
    }
}

// ================= Flash attention, f16 MFMA, key-split =================
// grid 256*nsplit, block 128 = 2 waves x 32 queries, BN=64 keys/step.
#define BM 64
#define BN 64
#define LK 136   // sK row stride (f16)
#define LV 88    // sVt row stride
#define LP 88    // sP row stride

__global__ __launch_bounds__(128, 2) void attn_mfma(
    const f16* __restrict__ Qh, const f16* __restrict__ Kh,
    const f16* __restrict__ Vh, float* __restrict__ out,
    float* __restrict__ Opart, float2* __restrict__ ml, int nsplit)
{
    __shared__ f16 sK[BN * LK];        // 17408 B
    __shared__ f16 sVt[HH * LV];       // 22528 B
    __shared__ f16 sP[2][32 * LP];     // 11264 B

    const int bid = blockIdx.x;
    const int split = bid >> 8;
    const int inner = bid & 255;
    const int batch = inner & 3;
    const int qtile = inner >> 2;
    const int t = threadIdx.x;
    const int w = t >> 6, lane = t & 63;
    const int c = lane & 15, quad = lane >> 4;

    // key range for this split (in BN-steps of the 64 total)
    const int s0 = (64 * split) / nsplit;
    const int s1 = (64 * (split + 1)) / nsplit;
    const int nst = s1 - s0;
    const int kstart = s0 * BN;

    const f16* Qb = Qh + (size_t)batch * SS * HH;
    const f16* Kb = Kh + (size_t)batch * SS * HH;
    const f16* Vb = Vh + (size_t)batch * SS * HH;
    const int qbase = qtile * BM + w * 32;

    // Q fragments (B-operand): n = lane&15, k = quad*8+j (+32*kc)
    f16x8 qf[2][4];
#pragma unroll
    for (int qt = 0; qt < 2; ++qt)
#pragma unroll
        for (int kc = 0; kc < 4; ++kc)
            qf[qt][kc] = *(const f16x8*)(Qb + (size_t)(qbase + qt * 16 + c) * HH + kc * 32 + quad * 8);

    // staging assignments
    const int kr = t >> 1, kh = t & 1;          // K: 2 threads/row
    const f16* kgp = Kb + (size_t)(kstart + kr) * HH + kh * 64;
    f16* ksp = sK + kr * LK + kh * 64;
    const int vkp = t & 31, vhq = t >> 5;       // V: key pair 2*vkp
    const f16* vgp = Vb + (size_t)(kstart + 2 * vkp) * HH;

    u32x4 kbuf[8], vb0[4], vb1[4];
#pragma unroll
    for (int i = 0; i < 8; ++i) kbuf[i] = *(const u32x4*)(kgp + i * 8);
#pragma unroll
    for (int p = 0; p < 4; ++p) {
        const int hg = vhq * 4 + p;
        vb0[p] = *(const u32x4*)(vgp + hg * 8);
        vb1[p] = *(const u32x4*)(vgp + HH + hg * 8);
    }

    f32x4 oacc[2][8];
#pragma unroll
    for (int mt = 0; mt < 2; ++mt)
#pragma unroll
        for (int nt = 0; nt < 8; ++nt) oacc[mt][nt] = (f32x4)0.f;
    float m_[2] = {-1e30f, -1e30f}, l_[2] = {0.f, 0.f};

    for (int st = 0; st < nst; ++st) {
        __syncthreads();
#pragma unroll
        for (int i = 0; i < 8; ++i) *(u32x4*)(ksp + i * 8) = kbuf[i];
#pragma unroll
        for (int p = 0; p < 4; ++p) {
            const int hg = vhq * 4 + p;
            VU a, b; a.v = vb0[p]; b.v = vb1[p];
#pragma unroll
            for (int i = 0; i < 8; ++i) {
                unsigned int pk = (unsigned int)a.s[i] | ((unsigned int)b.s[i] << 16);
                *(unsigned int*)&sVt[(hg * 8 + i) * LV + 2 * vkp] = pk;
            }
        }
        __syncthreads();
        if (st + 1 < nst) {
            const f16* kg = kgp + (size_t)(st + 1) * BN * HH;
#pragma unroll
            for (int i = 0; i < 8; ++i) kbuf[i] = *(const u32x4*)(kg + i * 8);
            const f16* vg = vgp + (size_t)(st + 1) * BN * HH;
#pragma unroll
            for (int p = 0; p < 4; ++p) {
                const int hg = vhq * 4 + p;
                vb0[p] = *(const u32x4*)(vg + hg * 8);
                vb1[p] = *(const u32x4*)(vg + HH + hg * 8);
            }
        }

        // ---- S^T = K . Q^T ----
        f32x4 sacc[4][2];
#pragma unroll
        for (int km = 0; km < 4; ++km)
#pragma unroll
            for (int qt = 0; qt < 2; ++qt) sacc[km][qt] = (f32x4)0.f;
#pragma unroll
        for (int kc = 0; kc < 4; ++kc) {
#pragma unroll
            for (int km = 0; km < 4; ++km) {
                f16x8 kf = *(const f16x8*)&sK[(km * 16 + c) * LK + kc * 32 + quad * 8];
#pragma unroll
                for (int qt = 0; qt < 2; ++qt)
                    sacc[km][qt] = __builtin_amdgcn_mfma_f32_16x16x32_f16(kf, qf[qt][kc], sacc[km][qt], 0, 0, 0);
            }
        }

        // ---- online softmax (per query col = lane&15, per qt) ----
        float alpha_s[2];
#pragma unroll
        for (int qt = 0; qt < 2; ++qt) {
            float mx = sacc[0][qt][0];
#pragma unroll
            for (int km = 0; km < 4; ++km)
#pragma unroll
                for (int r = 0; r < 4; ++r) mx = fmaxf(mx, sacc[km][qt][r]);
            mx = fmaxf(mx, __shfl_xor(mx, 16));
            mx = fmaxf(mx, __shfl_xor(mx, 32));
            const float mn = fmaxf(m_[qt], mx);
            const float alpha = exp2f((m_[qt] - mn) * SC2);
            m_[qt] = mn;
            alpha_s[qt] = alpha;
            const float tb = mn * SC2;
            float ls = 0.f;
#pragma unroll
            for (int km = 0; km < 4; ++km) {
                float p0 = exp2f(sacc[km][qt][0] * SC2 - tb);
                float p1 = exp2f(sacc[km][qt][1] * SC2 - tb);
                float p2 = exp2f(sacc[km][qt][2] * SC2 - tb);
                float p3 = exp2f(sacc[km][qt][3] * SC2 - tb);
                ls += (p0 + p1) + (p2 + p3);
                H2U u0, u1;
                u0.h = __floats2half2_rn(p0, p1);
                u1.h = __floats2half2_rn(p2, p3);
                u32x2 pk; pk.x = u0.u; pk.y = u1.u;
                *(u32x2*)&sP[w][(qt * 16 + c) * LP + km * 16 + quad * 4] = pk;
            }
            ls += __shfl_xor(ls, 16);
            ls += __shfl_xor(ls, 32);
            l_[qt] = l_[qt] * alpha + ls;
        }

        // ---- rescale O by alpha (broadcast via shuffles, no LDS) ----
#pragma unroll
        for (int mt = 0; mt < 2; ++mt) {
            float av[4];
#pragma unroll
            for (int r = 0; r < 4; ++r)
                av[r] = __shfl(alpha_s[mt], quad * 4 + r);
#pragma unroll
            for (int nt = 0; nt < 8; ++nt)
#pragma unroll
                for (int r = 0; r < 4; ++r) oacc[mt][nt][r] *= av[r];
        }

        // ---- O += P . V ----
#pragma unroll
        for (int kc2 = 0; kc2 < 2; ++kc2) {
            f16x8 pf[2];
#pragma unroll
            for (int mt = 0; mt < 2; ++mt)
                pf[mt] = *(const f16x8*)&sP[w][(mt * 16 + c) * LP + kc2 * 32 + quad * 8];
#pragma unroll
            for (int nt = 0; nt < 8; ++nt) {
                f16x8 vf = *(const f16x8*)&sVt[(nt * 16 + c) * LV + kc2 * 32 + quad * 8];
#pragma unroll
                for (int mt = 0; mt < 2; ++mt)
                    oacc[mt][nt] = __builtin_amdgcn_mfma_f32_16x16x32_f16(pf[mt], vf, oacc[mt][nt], 0, 0, 0);
            }
        }
    }

    // ---- epilogue ----
    float* Ob = (split == 0) ? out : (Opart + (size_t)(split - 1) * BB * SS * HH);
    float* ob = Ob + (size_t)(batch * SS + qbase) * HH;
    if (nsplit == 1) {
#pragma unroll
        for (int mt = 0; mt < 2; ++mt) {
            float lv[4];
#pragma unroll
            for (int r = 0; r < 4; ++r)
                lv[r] = 1.f / __shfl(l_[mt], quad * 4 + r);
#pragma unroll
            for (int r = 0; r < 4; ++r) {
                const int row = mt * 16 + quad * 4 + r;
#pragma unroll
                for (int nt = 0; nt < 8; ++nt)
                    ob[(size_t)row * HH + nt * 16 + c] = oacc[mt][nt][r] * lv[r];
            }
        }
    } else {
#pragma unroll
        for (int mt = 0; mt < 2; ++mt) {
#pragma unroll
            for (int r = 0; r < 4; ++r) {
                const int row = mt * 16 + quad * 4 + r;
#pragma unroll
                for (int nt = 0; nt < 8; ++nt)
                    ob[(size_t)row * HH + nt * 16 + c] = oacc[mt][nt][r];
            }
        }
        if (quad == 0) {
#pragma unroll
            for (int qt = 0; qt < 2; ++qt) {
                float2 v; v.x = m_[qt]; v.y = l_[qt];
                ml[((size_t)split * BB + batch) * SS + qbase + qt * 16 + c] = v;
            }
        }
    }
}

// ================= merge partials =================
__global__ __launch_bounds__(256) void attn_merge(
    float* __restrict__ out, const float* __restrict__ Opart,
    const float2* __restrict__ ml, int nsplit)
{
    const int idx = blockIdx.x * 256 + threadIdx.x;   // over BB*SS*(HH/4)
    const int chunk = idx & 31;
    const int q = (idx >> 5) & (SS - 1);
    const int b = idx >> 17;
    float m = -1e30f;
    for (int s = 0; s < nsplit; ++s)
        m = fmaxf(m, ml[((size_t)s * BB + b) * SS + q].x);
    float L = 0.f;
    float ax = 0.f, ay = 0.f, az = 0.f, aw = 0.f;
    for (int s = 0; s < nsplit; ++s) {
        float2 v = ml[((size_t)s * BB + b) * SS + q];
        const float wgt = exp2f((v.x - m) * SC2);
        L += v.y * wgt;
        const float* Op = (s == 0) ? out : (Opart + (size_t)(s - 1) * BB * SS * HH);
        float4 o = *(const float4*)(Op + ((size_t)b * SS + q) * HH + chunk * 4);
        ax += wgt * o.x; ay += wgt * o.y; az += wgt * o.z; aw += wgt * o.w;
    }
    const float inv = 1.f / L;
    float4 r; r.x = ax * inv; r.y = ay * inv; r.z = az * inv; r.w = aw * inv;
    *(float4*)(out + ((size_t)b * SS + q) * HH + chunk * 4) = r;
}

extern "C" void kernel_launch(void* const* d_in, const int* in_sizes, int n_in,
                              void* d_out, int out_size, void* d_ws, size_t ws_size,
                              hipStream_t stream) {
    const float* X = (const float*)d_in[0];
    const float* W = (const float*)d_in[1];
    const float* bias = (const float*)d_in[2];
    float* out = (float*)d_out;

    char* ws = (char*)d_ws;
    const size_t qkv_bytes = (size_t)3 * BB * SS * HH * sizeof(f16);   // 12.58 MB
    const size_t o_bytes   = (size_t)BB * SS * HH * sizeof(float);     // 8.39 MB
    const size_t ml_bytes  = (size_t)BB * SS * sizeof(float2);         // 128 KB / split

    int S = 1;
    if (ws_size >= qkv_bytes + 2 * o_bytes + 3 * ml_bytes) S = 3;
    else if (ws_size >= qkv_bytes + 1 * o_bytes + 2 * ml_bytes) S = 2;

    f16* Qh = (f16*)ws;
    f16* Kh = Qh + (size_t)BB * SS * HH;
    f16* Vh = Kh + (size_t)BB * SS * HH;
    float* Opart = (float*)(ws + qkv_bytes);
    float2* ml = (float2*)(ws + qkv_bytes + (size_t)(S - 1) * o_bytes);

    qkv_gemm<<<dim3(128, 6), 256, 0, stream>>>(X, W, bias, Qh, Kh, Vh);
    attn_mfma<<<256 * S, 128, 0, stream>>>(Qh, Kh, Vh, out, Opart, ml, S);
    if (S > 1)
        attn_merge<<<BB * SS * (HH / 4) / 256, 256, 0, stream>>>(out, Opart, ml, S);
}

// Round 5
// 138.170 us; speedup vs baseline: 12.3414x; 1.1401x over previous
//
#include <hip/hip_runtime.h>
#include <hip/hip_fp16.h>

typedef _Float16 f16;
typedef __attribute__((ext_vector_type(8))) _Float16 f16x8;
typedef __attribute__((ext_vector_type(4))) float f32x4;
typedef __attribute__((ext_vector_type(4))) unsigned int u32x4;
typedef __attribute__((ext_vector_type(2))) unsigned int u32x2;

#define BB 4
#define SS 4096
#define HH 128
// log2(e)/sqrt(128)
#define SC2 0.12752462157076558f

union H2U { __half2 h; unsigned int u; };
union VU { u32x4 v; unsigned short s[8]; };
union F8U { u32x4 u; f16x8 h; };

// ================= QKV projection: f16 MFMA GEMM =================
// grid (128, 3): by = 0/1/2 -> Q/K/V (128 output cols each). Block 256 thr.
// W tile [128][128] staged fp32->f16 in LDS; A-frags direct from global.
#define LW 136
__global__ __launch_bounds__(256) void qkv_gemm(
    const float* __restrict__ X, const float* __restrict__ W,
    const float* __restrict__ bias, f16* __restrict__ Qh,
    f16* __restrict__ Kh, f16* __restrict__ Vh)
{
    __shared__ f16 sW[128 * LW];
    const int bx = blockIdx.x, by = blockIdx.y;
    const int t = threadIdx.x;
    const int w = t >> 6, lane = t & 63;
    const int c = lane & 15, quad = lane >> 4;

    // A fragments straight from global (fp32 -> f16 in-register)
    f16x8 af[2][4];
    const int rbase = bx * 128 + w * 32;
#pragma unroll
    for (int mt = 0; mt < 2; ++mt) {
        const float* xr = X + (size_t)(rbase + mt * 16 + c) * HH + quad * 8;
#pragma unroll
        for (int kc = 0; kc < 4; ++kc) {
            float4 a = *(const float4*)(xr + kc * 32);
            float4 b = *(const float4*)(xr + kc * 32 + 4);
            H2U u0, u1, u2, u3;
            u0.h = __floats2half2_rn(a.x, a.y);
            u1.h = __floats2half2_rn(a.z, a.w);
            u2.h = __floats2half2_rn(b.x, b.y);
            u3.h = __floats2half2_rn(b.z, b.w);
            F8U pk; pk.u.x = u0.u; pk.u.y = u1.u; pk.u.z = u2.u; pk.u.w = u3.u;
            af[mt][kc] = pk.h;
        }
    }

    {   // stage W tile [128][128] fp32 -> f16 (coalesced: 2 thr/row)
        const int r = t >> 1, h = t & 1;
        const float* src = W + (size_t)(by * 128 + r) * HH + h * 64;
        f16* dst = sW + r * LW + h * 64;
#pragma unroll
        for (int i = 0; i < 16; ++i) {
            float4 v = ((const float4*)src)[i];
            __half2 a = __floats2half2_rn(v.x, v.y);
            __half2 b = __floats2half2_rn(v.z, v.w);
            ((__half2*)dst)[2 * i] = a;
            ((__half2*)dst)[2 * i + 1] = b;
        }
    }
    __syncthreads();

    f32x4 acc[2][8];
#pragma unroll
    for (int mt = 0; mt < 2; ++mt)
#pragma unroll
        for (int nt = 0; nt < 8; ++nt) acc[mt][nt] = (f32x4)0.f;

#pragma unroll
    for (int kc = 0; kc < 4; ++kc) {
#pragma unroll
        for (int nt = 0; nt < 8; ++nt) {
            f16x8 bf = *(const f16x8*)&sW[(nt * 16 + c) * LW + kc * 32 + quad * 8];
#pragma unroll
            for (int mt = 0; mt < 2; ++mt)
                acc[mt][nt] = __builtin_amdgcn_mfma_f32_16x16x32_f16(af[mt][kc], bf, acc[mt][nt], 0, 0, 0);
        }
    }

    // epilogue: bias add, f16 convert, store
    f16* outp = (by == 0) ? Qh : (by == 1) ? Kh : Vh;
#pragma unroll
    for (int nt = 0; nt < 8; ++nt) {
        const int cc = nt * 16 + c;
        const float bv = bias[by * 128 + cc];
#pragma unroll
        for (int mt = 0; mt < 2; ++mt) {
#pragma unroll
            for (int r = 0; r < 4; ++r) {
                const int row = rbase + mt * 16 + quad * 4 + r;
                outp[(size_t)row * HH + cc] = (f16)(acc[mt][nt][r] + bv);
            }
        }
    }
}

// ================= Flash attention, f16 MFMA, key-split =================
// BM=128 (block = 4 waves x 32 queries), BN=64 keys/step.
// grid = 128 * nsplit; 2 blocks/CU (LDS 54.3KB) -> 8 waves/CU.
#define BM 128
#define BN 64
#define LK 136   // sK row stride (f16)
#define LV 72    // sVt row stride
#define LP 72    // sP row stride

__global__ __launch_bounds__(256, 2) void attn_mfma(
    const f16* __restrict__ Qh, const f16* __restrict__ Kh,
    const f16* __restrict__ Vh, float* __restrict__ out,
    float* __restrict__ Opart, float2* __restrict__ ml, int nsplit)
{
    __shared__ f16 sK[BN * LK];        // 17408 B
    __shared__ f16 sVt[HH * LV];       // 18432 B
    __shared__ f16 sP[4][32 * LP];     // 18432 B

    const int bid = blockIdx.x;
    const int split = bid >> 7;
    const int inner = bid & 127;
    const int batch = inner & 3;
    const int qtile = inner >> 2;
    const int t = threadIdx.x;
    const int w = t >> 6, lane = t & 63;
    const int c = lane & 15, quad = lane >> 4;

    // key range for this split (in BN-steps of the 64 total)
    const int s0 = (64 * split) / nsplit;
    const int s1 = (64 * (split + 1)) / nsplit;
    const int nst = s1 - s0;
    const int kstart = s0 * BN;

    const f16* Qb = Qh + (size_t)batch * SS * HH;
    const f16* Kb = Kh + (size_t)batch * SS * HH;
    const f16* Vb = Vh + (size_t)batch * SS * HH;
    const int qbase = qtile * BM + w * 32;

    // Q fragments (B-operand): n = lane&15, k = quad*8+j (+32*kc)
    f16x8 qf[2][4];
#pragma unroll
    for (int qt = 0; qt < 2; ++qt)
#pragma unroll
        for (int kc = 0; kc < 4; ++kc)
            qf[qt][kc] = *(const f16x8*)(Qb + (size_t)(qbase + qt * 16 + c) * HH + kc * 32 + quad * 8);

    // staging assignments (256 threads)
    const int kr = t >> 2, q4 = t & 3;          // K: 4 thr/row, 64B each
    const f16* kgp = Kb + (size_t)(kstart + kr) * HH + q4 * 32;
    f16* ksp = sK + kr * LK + q4 * 32;
    const int vkp = t & 31, vhq = t >> 5;       // V: key pair 2*vkp, 16 dims
    const f16* vgp = Vb + (size_t)(kstart + 2 * vkp) * HH + vhq * 16;

    u32x4 kbuf[4], vb0[2], vb1[2];
#pragma unroll
    for (int i = 0; i < 4; ++i) kbuf[i] = *(const u32x4*)(kgp + i * 8);
#pragma unroll
    for (int i = 0; i < 2; ++i) {
        vb0[i] = *(const u32x4*)(vgp + i * 8);
        vb1[i] = *(const u32x4*)(vgp + HH + i * 8);
    }

    f32x4 oacc[2][8];
#pragma unroll
    for (int mt = 0; mt < 2; ++mt)
#pragma unroll
        for (int nt = 0; nt < 8; ++nt) oacc[mt][nt] = (f32x4)0.f;
    float m_[2] = {-1e30f, -1e30f}, l_[2] = {0.f, 0.f};

    for (int st = 0; st < nst; ++st) {
        __syncthreads();
#pragma unroll
        for (int i = 0; i < 4; ++i) *(u32x4*)(ksp + i * 8) = kbuf[i];
        {
            VU a0, a1, b0, b1;
            a0.v = vb0[0]; a1.v = vb0[1]; b0.v = vb1[0]; b1.v = vb1[1];
#pragma unroll
            for (int d = 0; d < 8; ++d) {
                unsigned int pk = (unsigned int)a0.s[d] | ((unsigned int)b0.s[d] << 16);
                *(unsigned int*)&sVt[(vhq * 16 + d) * LV + 2 * vkp] = pk;
            }
#pragma unroll
            for (int d = 0; d < 8; ++d) {
                unsigned int pk = (unsigned int)a1.s[d] | ((unsigned int)b1.s[d] << 16);
                *(unsigned int*)&sVt[(vhq * 16 + 8 + d) * LV + 2 * vkp] = pk;
            }
        }
        __syncthreads();
        if (st + 1 < nst) {
            const f16* kg = kgp + (size_t)(st + 1) * BN * HH;
#pragma unroll
            for (int i = 0; i < 4; ++i) kbuf[i] = *(const u32x4*)(kg + i * 8);
            const f16* vg = vgp + (size_t)(st + 1) * BN * HH;
#pragma unroll
            for (int i = 0; i < 2; ++i) {
                vb0[i] = *(const u32x4*)(vg + i * 8);
                vb1[i] = *(const u32x4*)(vg + HH + i * 8);
            }
        }

        // ---- S^T = K . Q^T ----
        f32x4 sacc[4][2];
#pragma unroll
        for (int km = 0; km < 4; ++km)
#pragma unroll
            for (int qt = 0; qt < 2; ++qt) sacc[km][qt] = (f32x4)0.f;
#pragma unroll
        for (int kc = 0; kc < 4; ++kc) {
#pragma unroll
            for (int km = 0; km < 4; ++km) {
                f16x8 kf = *(const f16x8*)&sK[(km * 16 + c) * LK + kc * 32 + quad * 8];
#pragma unroll
                for (int qt = 0; qt < 2; ++qt)
                    sacc[km][qt] = __builtin_amdgcn_mfma_f32_16x16x32_f16(kf, qf[qt][kc], sacc[km][qt], 0, 0, 0);
            }
        }

        // ---- online softmax (per query col = lane&15, per qt) ----
        float alpha_s[2];
#pragma unroll
        for (int qt = 0; qt < 2; ++qt) {
            float mx = sacc[0][qt][0];
#pragma unroll
            for (int km = 0; km < 4; ++km)
#pragma unroll
                for (int r = 0; r < 4; ++r) mx = fmaxf(mx, sacc[km][qt][r]);
            mx = fmaxf(mx, __shfl_xor(mx, 16));
            mx = fmaxf(mx, __shfl_xor(mx, 32));
            const float mn = fmaxf(m_[qt], mx);
            const float alpha = exp2f((m_[qt] - mn) * SC2);
            m_[qt] = mn;
            alpha_s[qt] = alpha;
            const float tb = mn * SC2;
            float ls = 0.f;
#pragma unroll
            for (int km = 0; km < 4; ++km) {
                float p0 = exp2f(sacc[km][qt][0] * SC2 - tb);
                float p1 = exp2f(sacc[km][qt][1] * SC2 - tb);
                float p2 = exp2f(sacc[km][qt][2] * SC2 - tb);
                float p3 = exp2f(sacc[km][qt][3] * SC2 - tb);
                ls += (p0 + p1) + (p2 + p3);
                H2U u0, u1;
                u0.h = __floats2half2_rn(p0, p1);
                u1.h = __floats2half2_rn(p2, p3);
                u32x2 pk; pk.x = u0.u; pk.y = u1.u;
                *(u32x2*)&sP[w][(qt * 16 + c) * LP + km * 16 + quad * 4] = pk;
            }
            ls += __shfl_xor(ls, 16);
            ls += __shfl_xor(ls, 32);
            l_[qt] = l_[qt] * alpha + ls;
        }

        // ---- rescale O by alpha (broadcast via shuffles) ----
#pragma unroll
        for (int mt = 0; mt < 2; ++mt) {
            float av[4];
#pragma unroll
            for (int r = 0; r < 4; ++r)
                av[r] = __shfl(alpha_s[mt], quad * 4 + r);
#pragma unroll
            for (int nt = 0; nt < 8; ++nt)
#pragma unroll
                for (int r = 0; r < 4; ++r) oacc[mt][nt][r] *= av[r];
        }

        // ---- O += P . V ----
#pragma unroll
        for (int kc2 = 0; kc2 < 2; ++kc2) {
            f16x8 pf[2];
#pragma unroll
            for (int mt = 0; mt < 2; ++mt)
                pf[mt] = *(const f16x8*)&sP[w][(mt * 16 + c) * LP + kc2 * 32 + quad * 8];
#pragma unroll
            for (int nt = 0; nt < 8; ++nt) {
                f16x8 vf = *(const f16x8*)&sVt[(nt * 16 + c) * LV + kc2 * 32 + quad * 8];
#pragma unroll
                for (int mt = 0; mt < 2; ++mt)
                    oacc[mt][nt] = __builtin_amdgcn_mfma_f32_16x16x32_f16(pf[mt], vf, oacc[mt][nt], 0, 0, 0);
            }
        }
    }

    // ---- epilogue ----
    float* Ob = (split == 0) ? out : (Opart + (size_t)(split - 1) * BB * SS * HH);
    float* ob = Ob + (size_t)(batch * SS + qbase) * HH;
    if (nsplit == 1) {
#pragma unroll
        for (int mt = 0; mt < 2; ++mt) {
            float lv[4];
#pragma unroll
            for (int r = 0; r < 4; ++r)
                lv[r] = 1.f / __shfl(l_[mt], quad * 4 + r);
#pragma unroll
            for (int r = 0; r < 4; ++r) {
                const int row = mt * 16 + quad * 4 + r;
#pragma unroll
                for (int nt = 0; nt < 8; ++nt)
                    ob[(size_t)row * HH + nt * 16 + c] = oacc[mt][nt][r] * lv[r];
            }
        }
    } else {
#pragma unroll
        for (int mt = 0; mt < 2; ++mt) {
#pragma unroll
            for (int r = 0; r < 4; ++r) {
                const int row = mt * 16 + quad * 4 + r;
#pragma unroll
                for (int nt = 0; nt < 8; ++nt)
                    ob[(size_t)row * HH + nt * 16 + c] = oacc[mt][nt][r];
            }
        }
        if (quad == 0) {
#pragma unroll
            for (int qt = 0; qt < 2; ++qt) {
                float2 v; v.x = m_[qt]; v.y = l_[qt];
                ml[((size_t)split * BB + batch) * SS + qbase + qt * 16 + c] = v;
            }
        }
    }
}

// ================= merge partials =================
__global__ __launch_bounds__(256) void attn_merge(
    float* __restrict__ out, const float* __restrict__ Opart,
    const float2* __restrict__ ml, int nsplit)
{
    const int idx = blockIdx.x * 256 + threadIdx.x;   // over BB*SS*(HH/4)
    const int chunk = idx & 31;
    const int q = (idx >> 5) & (SS - 1);
    const int b = idx >> 17;
    float m = -1e30f;
    for (int s = 0; s < nsplit; ++s)
        m = fmaxf(m, ml[((size_t)s * BB + b) * SS + q].x);
    float L = 0.f;
    float ax = 0.f, ay = 0.f, az = 0.f, aw = 0.f;
    for (int s = 0; s < nsplit; ++s) {
        float2 v = ml[((size_t)s * BB + b) * SS + q];
        const float wgt = exp2f((v.x - m) * SC2);
        L += v.y * wgt;
        const float* Op = (s == 0) ? out : (Opart + (size_t)(s - 1) * BB * SS * HH);
        float4 o = *(const float4*)(Op + ((size_t)b * SS + q) * HH + chunk * 4);
        ax += wgt * o.x; ay += wgt * o.y; az += wgt * o.z; aw += wgt * o.w;
    }
    const float inv = 1.f / L;
    float4 r; r.x = ax * inv; r.y = ay * inv; r.z = az * inv; r.w = aw * inv;
    *(float4*)(out + ((size_t)b * SS + q) * HH + chunk * 4) = r;
}

extern "C" void kernel_launch(void* const* d_in, const int* in_sizes, int n_in,
                              void* d_out, int out_size, void* d_ws, size_t ws_size,
                              hipStream_t stream) {
    const float* X = (const float*)d_in[0];
    const float* W = (const float*)d_in[1];
    const float* bias = (const float*)d_in[2];
    float* out = (float*)d_out;

    char* ws = (char*)d_ws;
    const size_t qkv_bytes = (size_t)3 * BB * SS * HH * sizeof(f16);   // 12.58 MB
    const size_t o_bytes   = (size_t)BB * SS * HH * sizeof(float);     // 8.39 MB
    const size_t ml_bytes  = (size_t)BB * SS * sizeof(float2);         // 128 KB / split

    int S = 1;
    for (int cand = 4; cand >= 2; --cand) {
        if (ws_size >= qkv_bytes + (size_t)(cand - 1) * o_bytes + (size_t)cand * ml_bytes) {
            S = cand; break;
        }
    }

    f16* Qh = (f16*)ws;
    f16* Kh = Qh + (size_t)BB * SS * HH;
    f16* Vh = Kh + (size_t)BB * SS * HH;
    float* Opart = (float*)(ws + qkv_bytes);
    float2* ml = (float2*)(ws + qkv_bytes + (size_t)(S - 1) * o_bytes);

    qkv_gemm<<<dim3(128, 3), 256, 0, stream>>>(X, W, bias, Qh, Kh, Vh);
    attn_mfma<<<128 * S, 256, 0, stream>>>(Qh, Kh, Vh, out, Opart, ml, S);
    if (S > 1)
        attn_merge<<<BB * SS * (HH / 4) / 256, 256, 0, stream>>>(out, Opart, ml, S);
}